// Round 10
// baseline (425.267 us; speedup 1.0000x reference)
//
#include <hip/hip_runtime.h>
#include <math.h>

#define B_  2
#define H_  64
#define W_  64
#define HW  4096
#define DM  96
#define DI  192
#define NS  4
#define RK  6
#define KD  2
#define LL  8192   // 2*HW

__device__ __forceinline__ float sigmoidf_(float x){ return 1.f/(1.f+__expf(-x)); }
__device__ __forceinline__ float4 rev4(float4 v){ return make_float4(v.w,v.z,v.y,v.x); }

// ---------------- K0: zero an accumulator buffer ----------------
__global__ void k_zero(float* __restrict__ p, int n){
  int i = blockIdx.x*256 + threadIdx.x;
  if (i < n) p[i] = 0.f;
}

// ---------------- K1: input projections -> channel-major [B,DI,HW] + fused channel sums ----------------
__global__ __launch_bounds__(256) void k_inproj(
    const float* __restrict__ xrgb, const float* __restrict__ xe,
    const float* __restrict__ wr,   const float* __restrict__ we,
    float* __restrict__ xrt, float* __restrict__ xet, float* __restrict__ sr)
{
  __shared__ float lsW[DI*100];
  __shared__ float lsum[DI];
  const int mod = blockIdx.z, b = blockIdx.y;
  const int hw0 = blockIdx.x * 64;
  const float* x  = mod ? xe  : xrgb;
  const float* Wp = mod ? we  : wr;
  float* out      = mod ? xet : xrt;
  const int tid = threadIdx.x;
  for (int t = tid; t < DI*DM; t += 256){
    int di = t / DM, kk = t - di*DM;
    lsW[di*100 + kk] = Wp[t];
  }
  if (tid < DI) lsum[tid] = 0.f;
  const int cg = tid & 31, slot = tid >> 5;   // 8 slots
  const int r0 = slot * 8;
  const float* xb = x + ((size_t)(b*HW) + hw0 + r0)*DM;
  float acc[8][6];
  #pragma unroll
  for (int i=0;i<8;i++)
    #pragma unroll
    for (int q=0;q<6;q++) acc[i][q]=0.f;
  __syncthreads();
  for (int kk4=0; kk4<DM/4; kk4++){
    float4 xv[8];
    #pragma unroll
    for (int i=0;i<8;i++) xv[i] = *(const float4*)(xb + (size_t)i*DM + kk4*4);
    #pragma unroll
    for (int q=0;q<6;q++){
      const float4 wv = *(const float4*)(&lsW[(cg+32*q)*100 + kk4*4]);
      #pragma unroll
      for (int i=0;i<8;i++){
        acc[i][q] = fmaf(xv[i].x, wv.x, acc[i][q]);
        acc[i][q] = fmaf(xv[i].y, wv.y, acc[i][q]);
        acc[i][q] = fmaf(xv[i].z, wv.z, acc[i][q]);
        acc[i][q] = fmaf(xv[i].w, wv.w, acc[i][q]);
      }
    }
  }
  #pragma unroll
  for (int q=0;q<6;q++){
    int di = cg + 32*q;
    float* ob = out + ((size_t)(b*DI + di))*HW + hw0 + r0;
    float ps = 0.f;
    #pragma unroll
    for (int i=0;i<8;i++){ ob[i] = acc[i][q]; ps += acc[i][q]; }
    atomicAdd(&lsum[di], ps);
  }
  __syncthreads();
  if (tid < DI) atomicAdd(&sr[((size_t)mod*B_ + b)*DI + tid], lsum[tid]);
}

// ---------------- K2: depthwise 3x3 conv + SiLU -> seq[B,DI,2HW] ----------------
__global__ __launch_bounds__(256) void k_conv(
    const float* __restrict__ xrt, const float* __restrict__ xet,
    const float* __restrict__ cwr, const float* __restrict__ cbr,
    const float* __restrict__ cwe, const float* __restrict__ cbe,
    float* __restrict__ seq)
{
  const int z = blockIdx.z; const int b = z >> 1, mod = z & 1;
  const int d = blockIdx.y;
  const float* in = (mod? xet:xrt) + ((size_t)b*DI + d)*HW;
  const float* wp = (mod? cwe:cwr) + d*9;
  const float  bias = (mod? cbe:cbr)[d];
  const int hw = blockIdx.x*256 + threadIdx.x;
  const int y = hw >> 6, x = hw & 63;
  float w[9];
  #pragma unroll
  for (int i=0;i<9;i++) w[i]=wp[i];
  float acc = bias;
  #pragma unroll
  for (int dy=-1;dy<=1;dy++){
    int yy = y+dy;
    if (yy<0||yy>=H_) continue;
    #pragma unroll
    for (int dx=-1;dx<=1;dx++){
      int xx = x+dx;
      if (xx<0||xx>=W_) continue;
      acc += in[yy*W_+xx]*w[(dy+1)*3 + dx+1];
    }
  }
  float v = acc * sigmoidf_(acc);
  seq[((size_t)b*DI + d)*LL + mod*HW + hw] = v;
}

// ---------------- K3: squeeze-excitation MLP (sr holds channel SUMS; scale by 1/HW) ----------------
__global__ void k_se(const float* __restrict__ sr,
                     const float* __restrict__ f11, const float* __restrict__ f12,
                     const float* __restrict__ f21, const float* __restrict__ f22,
                     float* __restrict__ ex)
{
  const int b = blockIdx.x, mod = blockIdx.y;
  const float* f1 = mod? f21:f11;
  const float* f2 = mod? f22:f12;
  __shared__ float s[DI];
  __shared__ float hid[12];
  const int t = threadIdx.x;
  s[t] = sr[((size_t)mod*B_ + b)*DI + t] * (1.f/HW);
  __syncthreads();
  if (t < 12){
    float a=0.f;
    for (int dd=0; dd<DI; dd++) a += f1[t*DI+dd]*s[dd];
    hid[t] = a * sigmoidf_(a);
  }
  __syncthreads();
  float a=0.f;
  #pragma unroll
  for (int h=0; h<12; h++) a += f2[t*12+h]*hid[h];
  ex[((size_t)mod*B_ + b)*DI + t] = sigmoidf_(a);
}

// ---------------- K4: x_proj of seq -> SoA planes P[bk][14][LL], dd-split x4 ----------------
__global__ __launch_bounds__(256) void k_proj(
    const float* __restrict__ seq, const float* __restrict__ xpw,
    float* __restrict__ P)
{
  __shared__ float lw[14*DI];
  __shared__ float part[3][14][66];
  const int b = blockIdx.z, k = blockIdx.y;
  const int j0 = blockIdx.x*64;
  const int tid = threadIdx.x;
  const int jl = tid & 63, dq = tid >> 6;   // dq: 0..3, 48 channels each
  const int j = j0 + jl;
  for (int t = tid; t < 14*DI; t += 256) lw[t] = xpw[(size_t)k*14*DI + t];
  __syncthreads();
  float acc[14];
  #pragma unroll
  for (int c=0;c<14;c++) acc[c]=0.f;
  const float* sp = seq + (size_t)b*DI*LL + (size_t)(dq*48)*LL + j;
  const float* lwq = lw + dq*48;
  for (int dd=0; dd<48; dd++){
    float s = sp[(size_t)dd*LL];
    #pragma unroll
    for (int cc=0; cc<14; cc++) acc[cc] = fmaf(lwq[cc*DI+dd], s, acc[cc]);
  }
  if (dq){
    #pragma unroll
    for (int cc=0; cc<14; cc++) part[dq-1][cc][jl] = acc[cc];
  }
  __syncthreads();
  if (dq == 0){
    const int bk = b*KD + k;
    float* Pb = P + (size_t)bk*14*LL;
    #pragma unroll
    for (int cc=0; cc<14; cc++){
      float v = acc[cc] + part[0][cc][jl] + part[1][cc][jl] + part[2][cc][jl];
      Pb[(size_t)cc*LL + j] = v;
    }
  }
}

// ---------------- K5: hybrid scan: 4 pos/thread serial + wave shfl-scan ----------------
#define GETC(v_, s_) ((s_)==0?(v_).x:((s_)==1?(v_).y:((s_)==2?(v_).z:(v_).w)))
#define NT8 8   // tiles of 1024

template<int KDIR, bool IPOW>
__device__ __forceinline__ void scan_impl(
    const float* __restrict__ sq, const float* __restrict__ Pb,
    const float* A, const float* dwv, float bias, float Dv,
    float* __restrict__ yo, float (*wc)[4][8], int t)
{
  const int lane = t & 63, w = t >> 6;
  float cH[NS] = {0.f,0.f,0.f,0.f};

  for (int tt=0; tt<NT8; ++tt){
    const int j0 = KDIR ? (LL - 1024*tt - 4*t - 4) : (1024*tt + 4*t);
    float4 f0 = *(const float4*)(Pb + 0*(size_t)LL + j0);
    float4 f1 = *(const float4*)(Pb + 1*(size_t)LL + j0);
    float4 f2 = *(const float4*)(Pb + 2*(size_t)LL + j0);
    float4 f3 = *(const float4*)(Pb + 3*(size_t)LL + j0);
    float4 f4v= *(const float4*)(Pb + 4*(size_t)LL + j0);
    float4 f5 = *(const float4*)(Pb + 5*(size_t)LL + j0);
    float4 fx = *(const float4*)(sq + j0);
    float4 b0 = *(const float4*)(Pb + 6*(size_t)LL + j0);
    float4 b1 = *(const float4*)(Pb + 7*(size_t)LL + j0);
    float4 b2 = *(const float4*)(Pb + 8*(size_t)LL + j0);
    float4 b3 = *(const float4*)(Pb + 9*(size_t)LL + j0);
    float4 c0 = *(const float4*)(Pb + 10*(size_t)LL + j0);
    float4 c1 = *(const float4*)(Pb + 11*(size_t)LL + j0);
    float4 c2 = *(const float4*)(Pb + 12*(size_t)LL + j0);
    float4 c3 = *(const float4*)(Pb + 13*(size_t)LL + j0);
    if (KDIR){
      f0=rev4(f0); f1=rev4(f1); f2=rev4(f2); f3=rev4(f3); f4v=rev4(f4v); f5=rev4(f5);
      fx=rev4(fx);
      b0=rev4(b0); b1=rev4(b1); b2=rev4(b2); b3=rev4(b3);
      c0=rev4(c0); c1=rev4(c1); c2=rev4(c2); c3=rev4(c3);
    }

    // per-position delta, du, decay factors aP0..aP3
    float del[4], du[4], aP0[4], aP1[4], aP2[4], aP3[4];
    #pragma unroll
    for (int i=0;i<4;i++){
      float acc = bias;
      acc = fmaf(dwv[0],GETC(f0,i),acc); acc = fmaf(dwv[1],GETC(f1,i),acc);
      acc = fmaf(dwv[2],GETC(f2,i),acc); acc = fmaf(dwv[3],GETC(f3,i),acc);
      acc = fmaf(dwv[4],GETC(f4v,i),acc); acc = fmaf(dwv[5],GETC(f5,i),acc);
      if (IPOW){
        float ex_ = __expf(acc);
        float dl  = (acc > 20.f) ? acc : __logf(1.f + ex_);
        del[i] = dl;
        float a0 = 1.f/(1.f + ex_);        // exp(-softplus(acc)) exactly
        float a1 = a0*a0;
        aP0[i]=a0; aP1[i]=a1; aP2[i]=a1*a0; aP3[i]=a1*a1;
      } else {
        float dl = (acc > 20.f) ? acc : __logf(1.f + __expf(acc));
        del[i] = dl;
        aP0[i]=__expf(dl*A[0]); aP1[i]=__expf(dl*A[1]);
        aP2[i]=__expf(dl*A[2]); aP3[i]=__expf(dl*A[3]);
      }
      du[i]  = del[i]*GETC(fx,i);
    }

    float lA[NS][4], lH[NS][4];
    #pragma unroll
    for (int n=0;n<NS;n++){
      float rA=1.f, rH=0.f;
      #pragma unroll
      for (int i=0;i<4;i++){
        float Bi = GETC((n==0?b0:n==1?b1:n==2?b2:b3), i);
        float ai = (n==0? aP0[i] : n==1? aP1[i] : n==2? aP2[i] : aP3[i]);
        rH = fmaf(ai, rH, du[i]*Bi);
        rA *= ai;
        lA[n][i]=rA; lH[n][i]=rH;
      }
    }

    float sA[NS], sH[NS];
    #pragma unroll
    for (int n=0;n<NS;n++){ sA[n]=lA[n][3]; sH[n]=lH[n][3]; }
    #pragma unroll
    for (int s=1; s<64; s<<=1){
      float pa[NS], ph[NS];
      #pragma unroll
      for (int n=0;n<NS;n++){ pa[n]=__shfl_up(sA[n],(unsigned)s,64); ph[n]=__shfl_up(sH[n],(unsigned)s,64); }
      if (lane >= s){
        #pragma unroll
        for (int n=0;n<NS;n++){ sH[n]=fmaf(sA[n],ph[n],sH[n]); sA[n]*=pa[n]; }
      }
    }
    float eA[NS], eH[NS];
    #pragma unroll
    for (int n=0;n<NS;n++){
      float xa = __shfl_up(sA[n],1u,64), xh = __shfl_up(sH[n],1u,64);
      eA[n] = lane ? xa : 1.f;
      eH[n] = lane ? xh : 0.f;
    }

    const int buf = tt & 1;
    if (lane == 63){
      #pragma unroll
      for (int n=0;n<NS;n++){ wc[buf][w][n]=sA[n]; wc[buf][w][4+n]=sH[n]; }
    }
    __syncthreads();

    float WA[NS]={1.f,1.f,1.f,1.f}, WH[NS]={0.f,0.f,0.f,0.f};
    float TA[NS]={1.f,1.f,1.f,1.f}, TH[NS]={0.f,0.f,0.f,0.f};
    #pragma unroll
    for (int ww=0; ww<4; ww++){
      #pragma unroll
      for (int n=0;n<NS;n++){
        float qa = wc[buf][ww][n], qh = wc[buf][ww][4+n];
        if (ww < w){ WH[n]=fmaf(qa,WH[n],qh); WA[n]*=qa; }
        TH[n]=fmaf(qa,TH[n],qh); TA[n]*=qa;
      }
    }

    float PH[NS];
    #pragma unroll
    for (int n=0;n<NS;n++){
      float GH = fmaf(WA[n], cH[n], WH[n]);
      PH[n] = fmaf(eA[n], GH, eH[n]);
    }

    float yv[4];
    #pragma unroll
    for (int i=0;i<4;i++){
      float y = Dv*GETC(fx,i);
      #pragma unroll
      for (int n=0;n<NS;n++){
        float h = fmaf(lA[n][i], PH[n], lH[n][i]);
        float Ci = GETC((n==0?c0:n==1?c1:n==2?c2:c3), i);
        y = fmaf(Ci, h, y);
      }
      yv[i] = y;
    }
    float4 o = make_float4(yv[0],yv[1],yv[2],yv[3]);
    if (KDIR) o = rev4(o);
    *(float4*)(yo + j0) = o;

    #pragma unroll
    for (int n=0;n<NS;n++) cH[n] = fmaf(TA[n], cH[n], TH[n]);
  }
}

__global__ __launch_bounds__(256, 3) void k_scan(
    const float* __restrict__ seq,  const float* __restrict__ P,
    const float* __restrict__ dtw,  const float* __restrict__ dtb,
    const float* __restrict__ Alogs,const float* __restrict__ Dsp,
    float* __restrict__ y0, float* __restrict__ y1)
{
  const int gid = blockIdx.x;
  const int d = gid % DI;
  const int k = (gid / DI) % KD;
  const int b = gid / (DI*KD);
  const int t = threadIdx.x;
  const int kd = k*DI + d;
  float A[NS];
  #pragma unroll
  for (int n=0;n<NS;n++) A[n] = -__expf(Alogs[kd*NS+n]);
  float dwv[RK];
  #pragma unroll
  for (int r=0;r<RK;r++) dwv[r] = dtw[kd*RK+r];
  const float bias = dtb[kd];
  const float Dv   = Dsp[kd];
  const float* sq = seq + ((size_t)b*DI + d)*LL;
  const int bk = b*KD + k;
  const float* Pb = P + (size_t)bk*14*LL;
  float* yo = (k ? y1 : y0) + ((size_t)b*DI + d)*LL;

  __shared__ float wc[2][4][8];

  // A = -exp(Alogs) with Alogs = log(arange(1..5)) -> integer multiples (checked at runtime)
  const float tol = 1e-5f * fabsf(A[0]);
  const bool ipow = (fabsf(A[1]-2.f*A[0])<tol) && (fabsf(A[2]-3.f*A[0])<tol)
                 && (fabsf(A[3]-4.f*A[0])<tol) && (fabsf(A[0]+1.f) < 1e-5f);

  if (ipow){
    if (k == 0) scan_impl<0,true>(sq, Pb, A, dwv, bias, Dv, yo, wc, t);
    else        scan_impl<1,true>(sq, Pb, A, dwv, bias, Dv, yo, wc, t);
  } else {
    if (k == 0) scan_impl<0,false>(sq, Pb, A, dwv, bias, Dv, yo, wc, t);
    else        scan_impl<1,false>(sq, Pb, A, dwv, bias, Dv, yo, wc, t);
  }
}

// ---------------- K6: fused merge + LayerNorm + SE + output GEMM half ----------------
#define LNP 200
__global__ __launch_bounds__(256) void k_outln(
    const float* __restrict__ y0, const float* __restrict__ y1,
    const float* __restrict__ ln1g, const float* __restrict__ ln1b,
    const float* __restrict__ ln2g, const float* __restrict__ ln2b,
    const float* __restrict__ ex,  const float* __restrict__ Wo,
    float* __restrict__ out)
{
  __shared__ float vx[32][LNP];       // [j-local][di], 800B row stride (16B aligned)
  __shared__ float lsW[DM*68];
  __shared__ float ps1[8][33], ps2[8][33];
  __shared__ float lmu[32], lrs[32];
  __shared__ float lgx[DI], lbx[DI];

  const int bid = blockIdx.x;          // 0..511
  const int ks  = bid & 1;             // modality / k-half
  const int rg  = bid >> 1;            // 0..255
  const int row0 = rg * 32;            // global row (b*HW + hw)
  const int b    = row0 >> 12;
  const int hw0  = row0 & (HW-1);
  const int seq0 = ks*HW + hw0;
  const int tid  = threadIdx.x;
  const int jl = tid & 31, dg = tid >> 5;   // 8 groups x 24 channels

  // LN params x excitation
  {
    const float* g  = ks? ln2g : ln1g;
    const float* bb = ks? ln2b : ln1b;
    const float* exm = ex + ((size_t)ks*B_ + b)*DI;
    if (tid < DI){ float e = exm[tid]; lgx[tid] = g[tid]*e; lbx[tid] = bb[tid]*e; }
  }

  // stage v = y0+y1 (coalesced along j), accumulate stats
  const float* p0 = y0 + (size_t)b*DI*LL + seq0;
  const float* p1 = y1 + (size_t)b*DI*LL + seq0;
  float s1=0.f, s2=0.f;
  for (int i=0;i<24;i++){
    int di = dg*24 + i;
    float v = p0[(size_t)di*LL + jl] + p1[(size_t)di*LL + jl];
    vx[jl][di] = v;
    s1 += v; s2 += v*v;
  }
  ps1[dg][jl]=s1; ps2[dg][jl]=s2;
  __syncthreads();
  if (tid < 32){
    float t1=0.f, t2=0.f;
    #pragma unroll
    for (int q=0;q<8;q++){ t1+=ps1[q][tid]; t2+=ps2[q][tid]; }
    float m  = t1*(1.f/DI);
    float var= t2*(1.f/DI) - m*m;
    lmu[tid]=m; lrs[tid]=rsqrtf(var + 1e-5f);
  }
  __syncthreads();
  // LN + SE transform in place
  {
    float m = lmu[jl], r = lrs[jl];
    for (int i=0;i<24;i++){
      int di = dg*24 + i;
      vx[jl][di] = fmaf((vx[jl][di]-m)*r, lgx[di], lbx[di]);
    }
  }
  __syncthreads();

  // GEMM: 8 slots x 4 rows, 3 dm-cols per thread
  const int cg = tid & 31, slot = tid >> 5;
  const int r0 = slot * 4;
  float acc[4][3];
  #pragma unroll
  for (int i=0;i<4;i++)
    #pragma unroll
    for (int q=0;q<3;q++) acc[i][q]=0.f;

  for (int c=0;c<3;c++){
    for (int t=tid; t<DM*64; t+=256){
      int dm = t>>6, kkl = t&63;
      lsW[dm*68 + kkl] = Wo[(size_t)dm*384 + ks*192 + c*64 + kkl];
    }
    __syncthreads();
    for (int kk4=0; kk4<16; kk4++){
      float4 xv[4];
      #pragma unroll
      for (int i=0;i<4;i++) xv[i] = *(const float4*)(&vx[r0+i][c*64 + kk4*4]);
      #pragma unroll
      for (int q=0;q<3;q++){
        const float4 wv = *(const float4*)(&lsW[(cg+32*q)*68 + kk4*4]);
        #pragma unroll
        for (int i=0;i<4;i++){
          acc[i][q] = fmaf(xv[i].x, wv.x, acc[i][q]);
          acc[i][q] = fmaf(xv[i].y, wv.y, acc[i][q]);
          acc[i][q] = fmaf(xv[i].z, wv.z, acc[i][q]);
          acc[i][q] = fmaf(xv[i].w, wv.w, acc[i][q]);
        }
      }
    }
    __syncthreads();
  }
  #pragma unroll
  for (int i=0;i<4;i++){
    float* ob = out + (size_t)(row0 + r0 + i)*DM;
    #pragma unroll
    for (int q=0;q<3;q++) atomicAdd(&ob[cg + 32*q], acc[i][q]);
  }
}

// ---------------- launch ----------------
extern "C" void kernel_launch(void* const* d_in, const int* in_sizes, int n_in,
                              void* d_out, int out_size, void* d_ws, size_t ws_size,
                              hipStream_t stream) {
  const float* x_rgb      = (const float*)d_in[0];
  const float* x_e        = (const float*)d_in[1];
  const float* in_proj_w  = (const float*)d_in[2];
  const float* in_proj_xw = (const float*)d_in[3];
  const float* conv_w     = (const float*)d_in[4];
  const float* conv_b     = (const float*)d_in[5];
  const float* conv_xw    = (const float*)d_in[6];
  const float* conv_xb    = (const float*)d_in[7];
  const float* xpw        = (const float*)d_in[8];
  const float* dtw        = (const float*)d_in[9];
  const float* dtb        = (const float*)d_in[10];
  const float* A_logs     = (const float*)d_in[11];
  const float* Ds         = (const float*)d_in[12];
  const float* ln1_g      = (const float*)d_in[13];
  const float* ln1_b      = (const float*)d_in[14];
  const float* ln2_g      = (const float*)d_in[15];
  const float* ln2_b      = (const float*)d_in[16];
  const float* out_proj_w = (const float*)d_in[17];
  const float* fc1_w1     = (const float*)d_in[18];
  const float* fc1_w2     = (const float*)d_in[19];
  const float* fc2_w1     = (const float*)d_in[20];
  const float* fc2_w2     = (const float*)d_in[21];

  float* ws = (float*)d_ws;
  float* xr_t = ws;                        // 1,572,864
  float* xe_t = ws + 1572864;              // 1,572,864
  float* y0   = ws;                        // 3,145,728 (alias)
  float* seq  = ws + 3145728;              // 3,145,728
  float* y1   = ws + 6291456;              // 3,145,728
  float* P    = ws + 9437184;              //   458,752
  float* sr   = ws + 9895936;              //       768
  float* ex   = ws + 9896704;              //       768
  float* outp = (float*)d_out;

  k_zero  <<<dim3(3), 256, 0, stream>>>(sr, 768);
  k_inproj<<<dim3(HW/64, B_, 2), 256, 0, stream>>>(x_rgb, x_e, in_proj_w, in_proj_xw, xr_t, xe_t, sr);
  k_conv  <<<dim3(HW/256, DI, B_*2), 256, 0, stream>>>(xr_t, xe_t, conv_w, conv_b, conv_xw, conv_xb, seq);
  k_se    <<<dim3(B_, 2), DI, 0, stream>>>(sr, fc1_w1, fc1_w2, fc2_w1, fc2_w2, ex);
  k_proj  <<<dim3(LL/64, KD, B_), 256, 0, stream>>>(seq, xpw, P);
  k_scan  <<<dim3(B_*KD*DI), 256, 0, stream>>>(seq, P, dtw, dtb, A_logs, Ds, y0, y1);
  k_zero  <<<dim3((B_*HW*DM + 255)/256), 256, 0, stream>>>(outp, B_*HW*DM);
  k_outln <<<dim3(512), 256, 0, stream>>>(y0, y1, ln1_g, ln1_b, ln2_g, ln2_b, ex, out_proj_w, outp);
}

// Round 11
// 138.760 us; speedup vs baseline: 3.0648x; 3.0648x over previous
//
#include <hip/hip_runtime.h>
#include <math.h>

#define B_  2
#define H_  64
#define W_  64
#define HW  4096
#define DM  96
#define DI  192
#define NS  4
#define RK  6
#define KD  2
#define LL  8192   // 2*HW

__device__ __forceinline__ float sigmoidf_(float x){ return 1.f/(1.f+__expf(-x)); }
__device__ __forceinline__ float4 rev4(float4 v){ return make_float4(v.w,v.z,v.y,v.x); }

// ---------------- K0: zero an accumulator buffer ----------------
__global__ void k_zero(float* __restrict__ p, int n){
  int i = blockIdx.x*256 + threadIdx.x;
  if (i < n) p[i] = 0.f;
}

// ---------------- K1: input projections -> channel-major [B,DI,HW] + fused channel sums ----------------
__global__ __launch_bounds__(256) void k_inproj(
    const float* __restrict__ xrgb, const float* __restrict__ xe,
    const float* __restrict__ wr,   const float* __restrict__ we,
    float* __restrict__ xrt, float* __restrict__ xet, float* __restrict__ sr)
{
  __shared__ float lsW[DI*100];
  __shared__ float lsum[DI];
  const int mod = blockIdx.z, b = blockIdx.y;
  const int hw0 = blockIdx.x * 64;
  const float* x  = mod ? xe  : xrgb;
  const float* Wp = mod ? we  : wr;
  float* out      = mod ? xet : xrt;
  const int tid = threadIdx.x;
  for (int t = tid; t < DI*DM; t += 256){
    int di = t / DM, kk = t - di*DM;
    lsW[di*100 + kk] = Wp[t];
  }
  if (tid < DI) lsum[tid] = 0.f;
  const int cg = tid & 31, slot = tid >> 5;   // 8 slots
  const int r0 = slot * 8;
  const float* xb = x + ((size_t)(b*HW) + hw0 + r0)*DM;
  float acc[8][6];
  #pragma unroll
  for (int i=0;i<8;i++)
    #pragma unroll
    for (int q=0;q<6;q++) acc[i][q]=0.f;
  __syncthreads();
  for (int kk4=0; kk4<DM/4; kk4++){
    float4 xv[8];
    #pragma unroll
    for (int i=0;i<8;i++) xv[i] = *(const float4*)(xb + (size_t)i*DM + kk4*4);
    #pragma unroll
    for (int q=0;q<6;q++){
      const float4 wv = *(const float4*)(&lsW[(cg+32*q)*100 + kk4*4]);
      #pragma unroll
      for (int i=0;i<8;i++){
        acc[i][q] = fmaf(xv[i].x, wv.x, acc[i][q]);
        acc[i][q] = fmaf(xv[i].y, wv.y, acc[i][q]);
        acc[i][q] = fmaf(xv[i].z, wv.z, acc[i][q]);
        acc[i][q] = fmaf(xv[i].w, wv.w, acc[i][q]);
      }
    }
  }
  #pragma unroll
  for (int q=0;q<6;q++){
    int di = cg + 32*q;
    float* ob = out + ((size_t)(b*DI + di))*HW + hw0 + r0;
    float ps = 0.f;
    #pragma unroll
    for (int i=0;i<8;i++){ ob[i] = acc[i][q]; ps += acc[i][q]; }
    atomicAdd(&lsum[di], ps);
  }
  __syncthreads();
  if (tid < DI) atomicAdd(&sr[((size_t)mod*B_ + b)*DI + tid], lsum[tid]);
}

// ---------------- K2: depthwise 3x3 conv + SiLU -> seq[B,DI,2HW] ----------------
__global__ __launch_bounds__(256) void k_conv(
    const float* __restrict__ xrt, const float* __restrict__ xet,
    const float* __restrict__ cwr, const float* __restrict__ cbr,
    const float* __restrict__ cwe, const float* __restrict__ cbe,
    float* __restrict__ seq)
{
  const int z = blockIdx.z; const int b = z >> 1, mod = z & 1;
  const int d = blockIdx.y;
  const float* in = (mod? xet:xrt) + ((size_t)b*DI + d)*HW;
  const float* wp = (mod? cwe:cwr) + d*9;
  const float  bias = (mod? cbe:cbr)[d];
  const int hw = blockIdx.x*256 + threadIdx.x;
  const int y = hw >> 6, x = hw & 63;
  float w[9];
  #pragma unroll
  for (int i=0;i<9;i++) w[i]=wp[i];
  float acc = bias;
  #pragma unroll
  for (int dy=-1;dy<=1;dy++){
    int yy = y+dy;
    if (yy<0||yy>=H_) continue;
    #pragma unroll
    for (int dx=-1;dx<=1;dx++){
      int xx = x+dx;
      if (xx<0||xx>=W_) continue;
      acc += in[yy*W_+xx]*w[(dy+1)*3 + dx+1];
    }
  }
  float v = acc * sigmoidf_(acc);
  seq[((size_t)b*DI + d)*LL + mod*HW + hw] = v;
}

// ---------------- K3: squeeze-excitation MLP (sr holds channel SUMS; scale by 1/HW) ----------------
__global__ void k_se(const float* __restrict__ sr,
                     const float* __restrict__ f11, const float* __restrict__ f12,
                     const float* __restrict__ f21, const float* __restrict__ f22,
                     float* __restrict__ ex)
{
  const int b = blockIdx.x, mod = blockIdx.y;
  const float* f1 = mod? f21:f11;
  const float* f2 = mod? f22:f12;
  __shared__ float s[DI];
  __shared__ float hid[12];
  const int t = threadIdx.x;
  s[t] = sr[((size_t)mod*B_ + b)*DI + t] * (1.f/HW);
  __syncthreads();
  if (t < 12){
    float a=0.f;
    for (int dd=0; dd<DI; dd++) a += f1[t*DI+dd]*s[dd];
    hid[t] = a * sigmoidf_(a);
  }
  __syncthreads();
  float a=0.f;
  #pragma unroll
  for (int h=0; h<12; h++) a += f2[t*12+h]*hid[h];
  ex[((size_t)mod*B_ + b)*DI + t] = sigmoidf_(a);
}

// ---------------- K4: x_proj of seq -> SoA planes P[bk][14][LL], dd-split x4 ----------------
__global__ __launch_bounds__(256) void k_proj(
    const float* __restrict__ seq, const float* __restrict__ xpw,
    float* __restrict__ P)
{
  __shared__ float lw[14*DI];
  __shared__ float part[3][14][66];
  const int b = blockIdx.z, k = blockIdx.y;
  const int j0 = blockIdx.x*64;
  const int tid = threadIdx.x;
  const int jl = tid & 63, dq = tid >> 6;   // dq: 0..3, 48 channels each
  const int j = j0 + jl;
  for (int t = tid; t < 14*DI; t += 256) lw[t] = xpw[(size_t)k*14*DI + t];
  __syncthreads();
  float acc[14];
  #pragma unroll
  for (int c=0;c<14;c++) acc[c]=0.f;
  const float* sp = seq + (size_t)b*DI*LL + (size_t)(dq*48)*LL + j;
  const float* lwq = lw + dq*48;
  for (int dd=0; dd<48; dd++){
    float s = sp[(size_t)dd*LL];
    #pragma unroll
    for (int cc=0; cc<14; cc++) acc[cc] = fmaf(lwq[cc*DI+dd], s, acc[cc]);
  }
  if (dq){
    #pragma unroll
    for (int cc=0; cc<14; cc++) part[dq-1][cc][jl] = acc[cc];
  }
  __syncthreads();
  if (dq == 0){
    const int bk = b*KD + k;
    float* Pb = P + (size_t)bk*14*LL;
    #pragma unroll
    for (int cc=0; cc<14; cc++){
      float v = acc[cc] + part[0][cc][jl] + part[1][cc][jl] + part[2][cc][jl];
      Pb[(size_t)cc*LL + j] = v;
    }
  }
}

// ---------------- K5: hybrid scan: 4 pos/thread serial + wave shfl-scan ----------------
#define GETC(v_, s_) ((s_)==0?(v_).x:((s_)==1?(v_).y:((s_)==2?(v_).z:(v_).w)))
#define NT8 8   // tiles of 1024

template<int KDIR, bool IPOW>
__device__ __forceinline__ void scan_impl(
    const float* __restrict__ sq, const float* __restrict__ Pb,
    const float* A, const float* dwv, float bias, float Dv,
    float* __restrict__ yo, float (*wc)[4][8], int t)
{
  const int lane = t & 63, w = t >> 6;
  float cH[NS] = {0.f,0.f,0.f,0.f};

  for (int tt=0; tt<NT8; ++tt){
    const int j0 = KDIR ? (LL - 1024*tt - 4*t - 4) : (1024*tt + 4*t);
    float4 f0 = *(const float4*)(Pb + 0*(size_t)LL + j0);
    float4 f1 = *(const float4*)(Pb + 1*(size_t)LL + j0);
    float4 f2 = *(const float4*)(Pb + 2*(size_t)LL + j0);
    float4 f3 = *(const float4*)(Pb + 3*(size_t)LL + j0);
    float4 f4v= *(const float4*)(Pb + 4*(size_t)LL + j0);
    float4 f5 = *(const float4*)(Pb + 5*(size_t)LL + j0);
    float4 fx = *(const float4*)(sq + j0);
    float4 b0 = *(const float4*)(Pb + 6*(size_t)LL + j0);
    float4 b1 = *(const float4*)(Pb + 7*(size_t)LL + j0);
    float4 b2 = *(const float4*)(Pb + 8*(size_t)LL + j0);
    float4 b3 = *(const float4*)(Pb + 9*(size_t)LL + j0);
    float4 c0 = *(const float4*)(Pb + 10*(size_t)LL + j0);
    float4 c1 = *(const float4*)(Pb + 11*(size_t)LL + j0);
    float4 c2 = *(const float4*)(Pb + 12*(size_t)LL + j0);
    float4 c3 = *(const float4*)(Pb + 13*(size_t)LL + j0);
    if (KDIR){
      f0=rev4(f0); f1=rev4(f1); f2=rev4(f2); f3=rev4(f3); f4v=rev4(f4v); f5=rev4(f5);
      fx=rev4(fx);
      b0=rev4(b0); b1=rev4(b1); b2=rev4(b2); b3=rev4(b3);
      c0=rev4(c0); c1=rev4(c1); c2=rev4(c2); c3=rev4(c3);
    }

    float del[4], du[4], aP0[4], aP1[4], aP2[4], aP3[4];
    #pragma unroll
    for (int i=0;i<4;i++){
      float acc = bias;
      acc = fmaf(dwv[0],GETC(f0,i),acc); acc = fmaf(dwv[1],GETC(f1,i),acc);
      acc = fmaf(dwv[2],GETC(f2,i),acc); acc = fmaf(dwv[3],GETC(f3,i),acc);
      acc = fmaf(dwv[4],GETC(f4v,i),acc); acc = fmaf(dwv[5],GETC(f5,i),acc);
      if (IPOW){
        float ex_ = __expf(acc);
        del[i] = (acc > 20.f) ? acc : __logf(1.f + ex_);
        float a0 = 1.f/(1.f + ex_);        // exp(-softplus(acc)) exactly
        float a1 = a0*a0;
        aP0[i]=a0; aP1[i]=a1; aP2[i]=a1*a0; aP3[i]=a1*a1;
      } else {
        float dl = (acc > 20.f) ? acc : __logf(1.f + __expf(acc));
        del[i] = dl;
        aP0[i]=__expf(dl*A[0]); aP1[i]=__expf(dl*A[1]);
        aP2[i]=__expf(dl*A[2]); aP3[i]=__expf(dl*A[3]);
      }
      du[i]  = del[i]*GETC(fx,i);
    }

    float lA[NS][4], lH[NS][4];
    #pragma unroll
    for (int n=0;n<NS;n++){
      float rA=1.f, rH=0.f;
      #pragma unroll
      for (int i=0;i<4;i++){
        float Bi = GETC((n==0?b0:n==1?b1:n==2?b2:b3), i);
        float ai = (n==0? aP0[i] : n==1? aP1[i] : n==2? aP2[i] : aP3[i]);
        rH = fmaf(ai, rH, du[i]*Bi);
        rA *= ai;
        lA[n][i]=rA; lH[n][i]=rH;
      }
    }

    float sA[NS], sH[NS];
    #pragma unroll
    for (int n=0;n<NS;n++){ sA[n]=lA[n][3]; sH[n]=lH[n][3]; }
    #pragma unroll
    for (int s=1; s<64; s<<=1){
      float pa[NS], ph[NS];
      #pragma unroll
      for (int n=0;n<NS;n++){ pa[n]=__shfl_up(sA[n],(unsigned)s,64); ph[n]=__shfl_up(sH[n],(unsigned)s,64); }
      if (lane >= s){
        #pragma unroll
        for (int n=0;n<NS;n++){ sH[n]=fmaf(sA[n],ph[n],sH[n]); sA[n]*=pa[n]; }
      }
    }
    float eA[NS], eH[NS];
    #pragma unroll
    for (int n=0;n<NS;n++){
      float xa = __shfl_up(sA[n],1u,64), xh = __shfl_up(sH[n],1u,64);
      eA[n] = lane ? xa : 1.f;
      eH[n] = lane ? xh : 0.f;
    }

    const int buf = tt & 1;
    if (lane == 63){
      #pragma unroll
      for (int n=0;n<NS;n++){ wc[buf][w][n]=sA[n]; wc[buf][w][4+n]=sH[n]; }
    }
    __syncthreads();

    float WA[NS]={1.f,1.f,1.f,1.f}, WH[NS]={0.f,0.f,0.f,0.f};
    float TA[NS]={1.f,1.f,1.f,1.f}, TH[NS]={0.f,0.f,0.f,0.f};
    #pragma unroll
    for (int ww=0; ww<4; ww++){
      #pragma unroll
      for (int n=0;n<NS;n++){
        float qa = wc[buf][ww][n], qh = wc[buf][ww][4+n];
        if (ww < w){ WH[n]=fmaf(qa,WH[n],qh); WA[n]*=qa; }
        TH[n]=fmaf(qa,TH[n],qh); TA[n]*=qa;
      }
    }

    float PH[NS];
    #pragma unroll
    for (int n=0;n<NS;n++){
      float GH = fmaf(WA[n], cH[n], WH[n]);
      PH[n] = fmaf(eA[n], GH, eH[n]);
    }

    float yv[4];
    #pragma unroll
    for (int i=0;i<4;i++){
      float y = Dv*GETC(fx,i);
      #pragma unroll
      for (int n=0;n<NS;n++){
        float h = fmaf(lA[n][i], PH[n], lH[n][i]);
        float Ci = GETC((n==0?c0:n==1?c1:n==2?c2:c3), i);
        y = fmaf(Ci, h, y);
      }
      yv[i] = y;
    }
    float4 o = make_float4(yv[0],yv[1],yv[2],yv[3]);
    if (KDIR) o = rev4(o);
    *(float4*)(yo + j0) = o;

    #pragma unroll
    for (int n=0;n<NS;n++) cH[n] = fmaf(TA[n], cH[n], TH[n]);
  }
}

__global__ __launch_bounds__(256, 3) void k_scan(
    const float* __restrict__ seq,  const float* __restrict__ P,
    const float* __restrict__ dtw,  const float* __restrict__ dtb,
    const float* __restrict__ Alogs,const float* __restrict__ Dsp,
    float* __restrict__ y0, float* __restrict__ y1)
{
  const int gid = blockIdx.x;
  const int d = gid % DI;
  const int k = (gid / DI) % KD;
  const int b = gid / (DI*KD);
  const int t = threadIdx.x;
  const int kd = k*DI + d;
  float A[NS];
  #pragma unroll
  for (int n=0;n<NS;n++) A[n] = -__expf(Alogs[kd*NS+n]);
  float dwv[RK];
  #pragma unroll
  for (int r=0;r<RK;r++) dwv[r] = dtw[kd*RK+r];
  const float bias = dtb[kd];
  const float Dv   = Dsp[kd];
  const float* sq = seq + ((size_t)b*DI + d)*LL;
  const int bk = b*KD + k;
  const float* Pb = P + (size_t)bk*14*LL;
  float* yo = (k ? y1 : y0) + ((size_t)b*DI + d)*LL;

  __shared__ float wc[2][4][8];

  // A = -exp(Alogs) -> integer multiples of A[0] = -1 (runtime-verified)
  const float tol = 1e-5f;
  const bool ipow = (fabsf(A[0]+1.f)<tol) && (fabsf(A[1]+2.f)<4.f*tol)
                 && (fabsf(A[2]+3.f)<tol*8.f) && (fabsf(A[3]+4.f)<tol*8.f);

  if (ipow){
    if (k == 0) scan_impl<0,true>(sq, Pb, A, dwv, bias, Dv, yo, wc, t);
    else        scan_impl<1,true>(sq, Pb, A, dwv, bias, Dv, yo, wc, t);
  } else {
    if (k == 0) scan_impl<0,false>(sq, Pb, A, dwv, bias, Dv, yo, wc, t);
    else        scan_impl<1,false>(sq, Pb, A, dwv, bias, Dv, yo, wc, t);
  }
}

// ---------------- K6: merge + LayerNorm + SE scale -> yln[B,L,DI] ----------------
__global__ __launch_bounds__(256) void k_ln(
    const float* __restrict__ y0, const float* __restrict__ y1,
    const float* __restrict__ ln1g, const float* __restrict__ ln1b,
    const float* __restrict__ ln2g, const float* __restrict__ ln2b,
    const float* __restrict__ ex, float* __restrict__ yln)
{
  const int b  = blockIdx.y;
  const int j0 = blockIdx.x*64;
  __shared__ float v[DI][65];
  __shared__ float ps1[4][64], ps2[4][64];
  __shared__ float mu[64], rs[64];
  const int tid = threadIdx.x;
  const int jl = tid & 63, ds = tid >> 6;
  const float* p0 = y0 + (size_t)b*DI*LL + j0;
  const float* p1 = y1 + (size_t)b*DI*LL + j0;
  for (int it=0; it<48; it++){
    int d = ds*48 + it;
    v[d][jl] = p0[(size_t)d*LL + jl] + p1[(size_t)d*LL + jl];
  }
  __syncthreads();
  float s1=0.f, s2=0.f;
  for (int it=0; it<48; it++){
    float x = v[ds*48+it][jl];
    s1 += x; s2 += x*x;
  }
  ps1[ds][jl]=s1; ps2[ds][jl]=s2;
  __syncthreads();
  if (tid < 64){
    float t1 = ps1[0][tid]+ps1[1][tid]+ps1[2][tid]+ps1[3][tid];
    float t2 = ps2[0][tid]+ps2[1][tid]+ps2[2][tid]+ps2[3][tid];
    float m  = t1*(1.f/DI);
    float var= t2*(1.f/DI) - m*m;
    mu[tid]=m; rs[tid]=rsqrtf(var + 1e-5f);
  }
  __syncthreads();
  const int mod = (j0 >= HW) ? 1 : 0;
  const float* g  = mod? ln2g:ln1g;
  const float* bb = mod? ln2b:ln1b;
  const float* exm = ex + ((size_t)mod*B_ + b)*DI;
  for (int it=0; it<48; it++){
    int idx = it*256 + tid;
    int j = idx / DI;
    int d = idx - j*DI;
    float x = v[d][j];
    float o = (x - mu[j])*rs[j]*g[d] + bb[d];
    o *= exm[d];
    yln[((size_t)b*LL + j0 + j)*DI + d] = o;
  }
}

// ---------------- K7: output projection, k-split x2 + atomicAdd ----------------
__global__ __launch_bounds__(128) void k_out(
    const float* __restrict__ yln, const float* __restrict__ Wo, float* __restrict__ out)
{
  __shared__ float lsW[DM*68];
  const int bid  = blockIdx.x;          // 0..511
  const int ks   = bid & 1;             // modality half of the 384-k reduction
  const int rg   = bid >> 1;            // 0..255 row group
  const int row0 = rg * 32;
  const int b    = row0 >> 12;
  const int hw0  = row0 & (HW-1);
  const int tid  = threadIdx.x;
  const int cg = tid & 31, slot = tid >> 5;   // 4 slots
  const int r0 = slot * 8;                    // 8 rows per thread
  float acc[8][3];
  #pragma unroll
  for (int i=0;i<8;i++)
    #pragma unroll
    for (int q=0;q<3;q++) acc[i][q]=0.f;

  const float* xrow = yln + ((size_t)b*LL + (ks ? HW+hw0 : hw0) + r0)*DI;
  for (int c=0;c<3;c++){
    const int colbase = ks*192 + c*64;
    for (int t=tid; t<DM*64; t+=128){
      int dm = t>>6, kkl = t&63;
      lsW[dm*68 + kkl] = Wo[(size_t)dm*384 + colbase + kkl];
    }
    __syncthreads();
    const float* xb = xrow + c*64;
    for (int kk4=0; kk4<16; kk4++){
      float4 xv[8];
      #pragma unroll
      for (int i=0;i<8;i++) xv[i] = *(const float4*)(xb + (size_t)i*DI + kk4*4);
      #pragma unroll
      for (int q=0;q<3;q++){
        const float4 wv = *(const float4*)(&lsW[(cg+32*q)*68 + kk4*4]);
        #pragma unroll
        for (int i=0;i<8;i++){
          acc[i][q] = fmaf(xv[i].x, wv.x, acc[i][q]);
          acc[i][q] = fmaf(xv[i].y, wv.y, acc[i][q]);
          acc[i][q] = fmaf(xv[i].z, wv.z, acc[i][q]);
          acc[i][q] = fmaf(xv[i].w, wv.w, acc[i][q]);
        }
      }
    }
    __syncthreads();
  }
  #pragma unroll
  for (int i=0;i<8;i++){
    float* ob = out + (size_t)(row0 + r0 + i)*DM;
    #pragma unroll
    for (int q=0;q<3;q++) atomicAdd(&ob[cg + 32*q], acc[i][q]);
  }
}

// ---------------- launch ----------------
extern "C" void kernel_launch(void* const* d_in, const int* in_sizes, int n_in,
                              void* d_out, int out_size, void* d_ws, size_t ws_size,
                              hipStream_t stream) {
  const float* x_rgb      = (const float*)d_in[0];
  const float* x_e        = (const float*)d_in[1];
  const float* in_proj_w  = (const float*)d_in[2];
  const float* in_proj_xw = (const float*)d_in[3];
  const float* conv_w     = (const float*)d_in[4];
  const float* conv_b     = (const float*)d_in[5];
  const float* conv_xw    = (const float*)d_in[6];
  const float* conv_xb    = (const float*)d_in[7];
  const float* xpw        = (const float*)d_in[8];
  const float* dtw        = (const float*)d_in[9];
  const float* dtb        = (const float*)d_in[10];
  const float* A_logs     = (const float*)d_in[11];
  const float* Ds         = (const float*)d_in[12];
  const float* ln1_g      = (const float*)d_in[13];
  const float* ln1_b      = (const float*)d_in[14];
  const float* ln2_g      = (const float*)d_in[15];
  const float* ln2_b      = (const float*)d_in[16];
  const float* out_proj_w = (const float*)d_in[17];
  const float* fc1_w1     = (const float*)d_in[18];
  const float* fc1_w2     = (const float*)d_in[19];
  const float* fc2_w1     = (const float*)d_in[20];
  const float* fc2_w2     = (const float*)d_in[21];

  float* ws = (float*)d_ws;
  float* xr_t = ws;                        // 1,572,864
  float* xe_t = ws + 1572864;              // 1,572,864
  float* y0   = ws;                        // 3,145,728 (alias)
  float* seq  = ws + 3145728;              // 3,145,728
  float* yln  = seq;                       // alias
  float* y1   = ws + 6291456;              // 3,145,728
  float* P    = ws + 9437184;              //   458,752
  float* sr   = ws + 9895936;              //       768
  float* ex   = ws + 9896704;              //       768
  float* outp = (float*)d_out;

  k_zero  <<<dim3(3), 256, 0, stream>>>(sr, 768);
  k_inproj<<<dim3(HW/64, B_, 2), 256, 0, stream>>>(x_rgb, x_e, in_proj_w, in_proj_xw, xr_t, xe_t, sr);
  k_conv  <<<dim3(HW/256, DI, B_*2), 256, 0, stream>>>(xr_t, xe_t, conv_w, conv_b, conv_xw, conv_xb, seq);
  k_se    <<<dim3(B_, 2), DI, 0, stream>>>(sr, fc1_w1, fc1_w2, fc2_w1, fc2_w2, ex);
  k_proj  <<<dim3(LL/64, KD, B_), 256, 0, stream>>>(seq, xpw, P);
  k_scan  <<<dim3(B_*KD*DI), 256, 0, stream>>>(seq, P, dtw, dtb, A_logs, Ds, y0, y1);
  k_ln    <<<dim3(LL/64, B_), 256, 0, stream>>>(y0, y1, ln1_g, ln1_b, ln2_g, ln2_b, ex, yln);
  k_zero  <<<dim3((B_*HW*DM + 255)/256), 256, 0, stream>>>(outp, B_*HW*DM);
  k_out   <<<dim3(512), 128, 0, stream>>>(yln, out_proj_w, outp);
}

// Round 12
// 138.674 us; speedup vs baseline: 3.0667x; 1.0006x over previous
//
#include <hip/hip_runtime.h>
#include <math.h>

#define B_  2
#define H_  64
#define W_  64
#define HW  4096
#define DM  96
#define DI  192
#define NS  4
#define RK  6
#define KD  2
#define LL  8192   // 2*HW

__device__ __forceinline__ float sigmoidf_(float x){ return 1.f/(1.f+__expf(-x)); }
__device__ __forceinline__ float4 rev4(float4 v){ return make_float4(v.w,v.z,v.y,v.x); }

// ---------------- K0: zero an accumulator buffer ----------------
__global__ void k_zero(float* __restrict__ p, int n){
  int i = blockIdx.x*256 + threadIdx.x;
  if (i < n) p[i] = 0.f;
}

// ---------------- K1: input projections -> channel-major [B,DI,HW] + fused channel sums ----------------
__global__ __launch_bounds__(256) void k_inproj(
    const float* __restrict__ xrgb, const float* __restrict__ xe,
    const float* __restrict__ wr,   const float* __restrict__ we,
    float* __restrict__ xrt, float* __restrict__ xet, float* __restrict__ sr)
{
  __shared__ float lsW[DI*100];
  __shared__ float lsum[DI];
  const int mod = blockIdx.z, b = blockIdx.y;
  const int hw0 = blockIdx.x * 64;
  const float* x  = mod ? xe  : xrgb;
  const float* Wp = mod ? we  : wr;
  float* out      = mod ? xet : xrt;
  const int tid = threadIdx.x;
  for (int t = tid; t < DI*DM; t += 256){
    int di = t / DM, kk = t - di*DM;
    lsW[di*100 + kk] = Wp[t];
  }
  if (tid < DI) lsum[tid] = 0.f;
  const int cg = tid & 31, slot = tid >> 5;   // 8 slots
  const int r0 = slot * 8;
  const float* xb = x + ((size_t)(b*HW) + hw0 + r0)*DM;
  float acc[8][6];
  #pragma unroll
  for (int i=0;i<8;i++)
    #pragma unroll
    for (int q=0;q<6;q++) acc[i][q]=0.f;
  __syncthreads();
  for (int kk4=0; kk4<DM/4; kk4++){
    float4 xv[8];
    #pragma unroll
    for (int i=0;i<8;i++) xv[i] = *(const float4*)(xb + (size_t)i*DM + kk4*4);
    #pragma unroll
    for (int q=0;q<6;q++){
      const float4 wv = *(const float4*)(&lsW[(cg+32*q)*100 + kk4*4]);
      #pragma unroll
      for (int i=0;i<8;i++){
        acc[i][q] = fmaf(xv[i].x, wv.x, acc[i][q]);
        acc[i][q] = fmaf(xv[i].y, wv.y, acc[i][q]);
        acc[i][q] = fmaf(xv[i].z, wv.z, acc[i][q]);
        acc[i][q] = fmaf(xv[i].w, wv.w, acc[i][q]);
      }
    }
  }
  #pragma unroll
  for (int q=0;q<6;q++){
    int di = cg + 32*q;
    float* ob = out + ((size_t)(b*DI + di))*HW + hw0 + r0;
    float ps = 0.f;
    #pragma unroll
    for (int i=0;i<8;i++){ ob[i] = acc[i][q]; ps += acc[i][q]; }
    atomicAdd(&lsum[di], ps);
  }
  __syncthreads();
  if (tid < DI) atomicAdd(&sr[((size_t)mod*B_ + b)*DI + tid], lsum[tid]);
}

// ---------------- K2: depthwise 3x3 conv + SiLU -> seq[B,DI,2HW] ----------------
__global__ __launch_bounds__(256) void k_conv(
    const float* __restrict__ xrt, const float* __restrict__ xet,
    const float* __restrict__ cwr, const float* __restrict__ cbr,
    const float* __restrict__ cwe, const float* __restrict__ cbe,
    float* __restrict__ seq)
{
  const int z = blockIdx.z; const int b = z >> 1, mod = z & 1;
  const int d = blockIdx.y;
  const float* in = (mod? xet:xrt) + ((size_t)b*DI + d)*HW;
  const float* wp = (mod? cwe:cwr) + d*9;
  const float  bias = (mod? cbe:cbr)[d];
  const int hw = blockIdx.x*256 + threadIdx.x;
  const int y = hw >> 6, x = hw & 63;
  float w[9];
  #pragma unroll
  for (int i=0;i<9;i++) w[i]=wp[i];
  float acc = bias;
  #pragma unroll
  for (int dy=-1;dy<=1;dy++){
    int yy = y+dy;
    if (yy<0||yy>=H_) continue;
    #pragma unroll
    for (int dx=-1;dx<=1;dx++){
      int xx = x+dx;
      if (xx<0||xx>=W_) continue;
      acc += in[yy*W_+xx]*w[(dy+1)*3 + dx+1];
    }
  }
  float v = acc * sigmoidf_(acc);
  seq[((size_t)b*DI + d)*LL + mod*HW + hw] = v;
}

// ---------------- K3: squeeze-excitation MLP (sr holds channel SUMS; scale by 1/HW) ----------------
__global__ void k_se(const float* __restrict__ sr,
                     const float* __restrict__ f11, const float* __restrict__ f12,
                     const float* __restrict__ f21, const float* __restrict__ f22,
                     float* __restrict__ ex)
{
  const int b = blockIdx.x, mod = blockIdx.y;
  const float* f1 = mod? f21:f11;
  const float* f2 = mod? f22:f12;
  __shared__ float s[DI];
  __shared__ float hid[12];
  const int t = threadIdx.x;
  s[t] = sr[((size_t)mod*B_ + b)*DI + t] * (1.f/HW);
  __syncthreads();
  if (t < 12){
    float a=0.f;
    for (int dd=0; dd<DI; dd++) a += f1[t*DI+dd]*s[dd];
    hid[t] = a * sigmoidf_(a);
  }
  __syncthreads();
  float a=0.f;
  #pragma unroll
  for (int h=0; h<12; h++) a += f2[t*12+h]*hid[h];
  ex[((size_t)mod*B_ + b)*DI + t] = sigmoidf_(a);
}

// ---------------- K4: x_proj of seq -> SoA planes P[bk][14][LL], dd-split x4 ----------------
__global__ __launch_bounds__(256) void k_proj(
    const float* __restrict__ seq, const float* __restrict__ xpw,
    float* __restrict__ P)
{
  __shared__ float lw[14*DI];
  __shared__ float part[3][14][66];
  const int b = blockIdx.z, k = blockIdx.y;
  const int j0 = blockIdx.x*64;
  const int tid = threadIdx.x;
  const int jl = tid & 63, dq = tid >> 6;   // dq: 0..3, 48 channels each
  const int j = j0 + jl;
  for (int t = tid; t < 14*DI; t += 256) lw[t] = xpw[(size_t)k*14*DI + t];
  __syncthreads();
  float acc[14];
  #pragma unroll
  for (int c=0;c<14;c++) acc[c]=0.f;
  const float* sp = seq + (size_t)b*DI*LL + (size_t)(dq*48)*LL + j;
  const float* lwq = lw + dq*48;
  for (int dd=0; dd<48; dd++){
    float s = sp[(size_t)dd*LL];
    #pragma unroll
    for (int cc=0; cc<14; cc++) acc[cc] = fmaf(lwq[cc*DI+dd], s, acc[cc]);
  }
  if (dq){
    #pragma unroll
    for (int cc=0; cc<14; cc++) part[dq-1][cc][jl] = acc[cc];
  }
  __syncthreads();
  if (dq == 0){
    const int bk = b*KD + k;
    float* Pb = P + (size_t)bk*14*LL;
    #pragma unroll
    for (int cc=0; cc<14; cc++){
      float v = acc[cc] + part[0][cc][jl] + part[1][cc][jl] + part[2][cc][jl];
      Pb[(size_t)cc*LL + j] = v;
    }
  }
}

// ---------------- K5: hybrid scan: 4 pos/thread serial + wave shfl-scan, prefetched ----------------
#define GETC(v_, s_) ((s_)==0?(v_).x:((s_)==1?(v_).y:((s_)==2?(v_).z:(v_).w)))
#define NT8 8   // tiles of 1024

template<int KDIR, bool IPOW>
__device__ __forceinline__ void scan_impl(
    const float* __restrict__ sq, const float* __restrict__ Pb,
    const float* A, const float* dwv, float bias, float Dv,
    float* __restrict__ yo, float (*wc)[4][8], int t)
{
  const int lane = t & 63, w = t >> 6;
  float cH[NS] = {0.f,0.f,0.f,0.f};

  // prefetch tile 0's critical streams (dt0-5, x)
  int jn = KDIR ? (LL - 4*t - 4) : (4*t);
  float4 pf0 = *(const float4*)(Pb + 0*(size_t)LL + jn);
  float4 pf1 = *(const float4*)(Pb + 1*(size_t)LL + jn);
  float4 pf2 = *(const float4*)(Pb + 2*(size_t)LL + jn);
  float4 pf3 = *(const float4*)(Pb + 3*(size_t)LL + jn);
  float4 pf4 = *(const float4*)(Pb + 4*(size_t)LL + jn);
  float4 pf5 = *(const float4*)(Pb + 5*(size_t)LL + jn);
  float4 pfx = *(const float4*)(sq + jn);

  for (int tt=0; tt<NT8; ++tt){
    const int j0 = jn;
    float4 f0=pf0, f1=pf1, f2=pf2, f3=pf3, f4v=pf4, f5=pf5, fx=pfx;
    // B/C for current tile: issued here, consumed 100-600 cyc later (self-hiding)
    float4 b0 = *(const float4*)(Pb + 6*(size_t)LL + j0);
    float4 b1 = *(const float4*)(Pb + 7*(size_t)LL + j0);
    float4 b2 = *(const float4*)(Pb + 8*(size_t)LL + j0);
    float4 b3 = *(const float4*)(Pb + 9*(size_t)LL + j0);
    float4 c0 = *(const float4*)(Pb + 10*(size_t)LL + j0);
    float4 c1 = *(const float4*)(Pb + 11*(size_t)LL + j0);
    float4 c2 = *(const float4*)(Pb + 12*(size_t)LL + j0);
    float4 c3 = *(const float4*)(Pb + 13*(size_t)LL + j0);

    // issue next tile's critical-stream prefetch (hidden under this tile's compute)
    if (tt+1 < NT8){
      jn = KDIR ? (LL - 1024*(tt+1) - 4*t - 4) : (1024*(tt+1) + 4*t);
      pf0 = *(const float4*)(Pb + 0*(size_t)LL + jn);
      pf1 = *(const float4*)(Pb + 1*(size_t)LL + jn);
      pf2 = *(const float4*)(Pb + 2*(size_t)LL + jn);
      pf3 = *(const float4*)(Pb + 3*(size_t)LL + jn);
      pf4 = *(const float4*)(Pb + 4*(size_t)LL + jn);
      pf5 = *(const float4*)(Pb + 5*(size_t)LL + jn);
      pfx = *(const float4*)(sq + jn);
    }

    if (KDIR){
      f0=rev4(f0); f1=rev4(f1); f2=rev4(f2); f3=rev4(f3); f4v=rev4(f4v); f5=rev4(f5);
      fx=rev4(fx);
      b0=rev4(b0); b1=rev4(b1); b2=rev4(b2); b3=rev4(b3);
      c0=rev4(c0); c1=rev4(c1); c2=rev4(c2); c3=rev4(c3);
    }

    float del[4], du[4], aP0[4], aP1[4], aP2[4], aP3[4];
    #pragma unroll
    for (int i=0;i<4;i++){
      float acc = bias;
      acc = fmaf(dwv[0],GETC(f0,i),acc); acc = fmaf(dwv[1],GETC(f1,i),acc);
      acc = fmaf(dwv[2],GETC(f2,i),acc); acc = fmaf(dwv[3],GETC(f3,i),acc);
      acc = fmaf(dwv[4],GETC(f4v,i),acc); acc = fmaf(dwv[5],GETC(f5,i),acc);
      if (IPOW){
        float ex_ = __expf(acc);
        del[i] = (acc > 20.f) ? acc : __logf(1.f + ex_);
        float a0 = 1.f/(1.f + ex_);        // exp(-softplus(acc)) exactly
        float a1 = a0*a0;
        aP0[i]=a0; aP1[i]=a1; aP2[i]=a1*a0; aP3[i]=a1*a1;
      } else {
        float dl = (acc > 20.f) ? acc : __logf(1.f + __expf(acc));
        del[i] = dl;
        aP0[i]=__expf(dl*A[0]); aP1[i]=__expf(dl*A[1]);
        aP2[i]=__expf(dl*A[2]); aP3[i]=__expf(dl*A[3]);
      }
      du[i]  = del[i]*GETC(fx,i);
    }

    float lA[NS][4], lH[NS][4];
    #pragma unroll
    for (int n=0;n<NS;n++){
      float rA=1.f, rH=0.f;
      #pragma unroll
      for (int i=0;i<4;i++){
        float Bi = GETC((n==0?b0:n==1?b1:n==2?b2:b3), i);
        float ai = (n==0? aP0[i] : n==1? aP1[i] : n==2? aP2[i] : aP3[i]);
        rH = fmaf(ai, rH, du[i]*Bi);
        rA *= ai;
        lA[n][i]=rA; lH[n][i]=rH;
      }
    }

    float sA[NS], sH[NS];
    #pragma unroll
    for (int n=0;n<NS;n++){ sA[n]=lA[n][3]; sH[n]=lH[n][3]; }
    #pragma unroll
    for (int s=1; s<64; s<<=1){
      float pa[NS], ph[NS];
      #pragma unroll
      for (int n=0;n<NS;n++){ pa[n]=__shfl_up(sA[n],(unsigned)s,64); ph[n]=__shfl_up(sH[n],(unsigned)s,64); }
      if (lane >= s){
        #pragma unroll
        for (int n=0;n<NS;n++){ sH[n]=fmaf(sA[n],ph[n],sH[n]); sA[n]*=pa[n]; }
      }
    }
    float eA[NS], eH[NS];
    #pragma unroll
    for (int n=0;n<NS;n++){
      float xa = __shfl_up(sA[n],1u,64), xh = __shfl_up(sH[n],1u,64);
      eA[n] = lane ? xa : 1.f;
      eH[n] = lane ? xh : 0.f;
    }

    const int buf = tt & 1;
    if (lane == 63){
      #pragma unroll
      for (int n=0;n<NS;n++){ wc[buf][w][n]=sA[n]; wc[buf][w][4+n]=sH[n]; }
    }
    __syncthreads();

    float WA[NS]={1.f,1.f,1.f,1.f}, WH[NS]={0.f,0.f,0.f,0.f};
    float TA[NS]={1.f,1.f,1.f,1.f}, TH[NS]={0.f,0.f,0.f,0.f};
    #pragma unroll
    for (int ww=0; ww<4; ww++){
      #pragma unroll
      for (int n=0;n<NS;n++){
        float qa = wc[buf][ww][n], qh = wc[buf][ww][4+n];
        if (ww < w){ WH[n]=fmaf(qa,WH[n],qh); WA[n]*=qa; }
        TH[n]=fmaf(qa,TH[n],qh); TA[n]*=qa;
      }
    }

    float PH[NS];
    #pragma unroll
    for (int n=0;n<NS;n++){
      float GH = fmaf(WA[n], cH[n], WH[n]);
      PH[n] = fmaf(eA[n], GH, eH[n]);
    }

    float yv[4];
    #pragma unroll
    for (int i=0;i<4;i++){
      float y = Dv*GETC(fx,i);
      #pragma unroll
      for (int n=0;n<NS;n++){
        float h = fmaf(lA[n][i], PH[n], lH[n][i]);
        float Ci = GETC((n==0?c0:n==1?c1:n==2?c2:c3), i);
        y = fmaf(Ci, h, y);
      }
      yv[i] = y;
    }
    float4 o = make_float4(yv[0],yv[1],yv[2],yv[3]);
    if (KDIR) o = rev4(o);
    *(float4*)(yo + j0) = o;

    #pragma unroll
    for (int n=0;n<NS;n++) cH[n] = fmaf(TA[n], cH[n], TH[n]);
  }
}

__global__ __launch_bounds__(256, 3) void k_scan(
    const float* __restrict__ seq,  const float* __restrict__ P,
    const float* __restrict__ dtw,  const float* __restrict__ dtb,
    const float* __restrict__ Alogs,const float* __restrict__ Dsp,
    float* __restrict__ y0, float* __restrict__ y1)
{
  const int gid = blockIdx.x;
  const int d = gid % DI;
  const int k = (gid / DI) % KD;
  const int b = gid / (DI*KD);
  const int t = threadIdx.x;
  const int kd = k*DI + d;
  float A[NS];
  #pragma unroll
  for (int n=0;n<NS;n++) A[n] = -__expf(Alogs[kd*NS+n]);
  float dwv[RK];
  #pragma unroll
  for (int r=0;r<RK;r++) dwv[r] = dtw[kd*RK+r];
  const float bias = dtb[kd];
  const float Dv   = Dsp[kd];
  const float* sq = seq + ((size_t)b*DI + d)*LL;
  const int bk = b*KD + k;
  const float* Pb = P + (size_t)bk*14*LL;
  float* yo = (k ? y1 : y0) + ((size_t)b*DI + d)*LL;

  __shared__ float wc[2][4][8];

  // A = -exp(Alogs) -> integer multiples of A[0] = -1 (runtime-verified)
  const float tol = 1e-5f;
  const bool ipow = (fabsf(A[0]+1.f)<tol) && (fabsf(A[1]+2.f)<4.f*tol)
                 && (fabsf(A[2]+3.f)<tol*8.f) && (fabsf(A[3]+4.f)<tol*8.f);

  if (ipow){
    if (k == 0) scan_impl<0,true>(sq, Pb, A, dwv, bias, Dv, yo, wc, t);
    else        scan_impl<1,true>(sq, Pb, A, dwv, bias, Dv, yo, wc, t);
  } else {
    if (k == 0) scan_impl<0,false>(sq, Pb, A, dwv, bias, Dv, yo, wc, t);
    else        scan_impl<1,false>(sq, Pb, A, dwv, bias, Dv, yo, wc, t);
  }
}

// ---------------- K6: merge + LayerNorm + SE scale -> yln[B,L,DI] ----------------
__global__ __launch_bounds__(256) void k_ln(
    const float* __restrict__ y0, const float* __restrict__ y1,
    const float* __restrict__ ln1g, const float* __restrict__ ln1b,
    const float* __restrict__ ln2g, const float* __restrict__ ln2b,
    const float* __restrict__ ex, float* __restrict__ yln)
{
  const int b  = blockIdx.y;
  const int j0 = blockIdx.x*64;
  __shared__ float v[DI][65];
  __shared__ float ps1[4][64], ps2[4][64];
  __shared__ float mu[64], rs[64];
  const int tid = threadIdx.x;
  const int jl = tid & 63, ds = tid >> 6;
  const float* p0 = y0 + (size_t)b*DI*LL + j0;
  const float* p1 = y1 + (size_t)b*DI*LL + j0;
  for (int it=0; it<48; it++){
    int d = ds*48 + it;
    v[d][jl] = p0[(size_t)d*LL + jl] + p1[(size_t)d*LL + jl];
  }
  __syncthreads();
  float s1=0.f, s2=0.f;
  for (int it=0; it<48; it++){
    float x = v[ds*48+it][jl];
    s1 += x; s2 += x*x;
  }
  ps1[ds][jl]=s1; ps2[ds][jl]=s2;
  __syncthreads();
  if (tid < 64){
    float t1 = ps1[0][tid]+ps1[1][tid]+ps1[2][tid]+ps1[3][tid];
    float t2 = ps2[0][tid]+ps2[1][tid]+ps2[2][tid]+ps2[3][tid];
    float m  = t1*(1.f/DI);
    float var= t2*(1.f/DI) - m*m;
    mu[tid]=m; rs[tid]=rsqrtf(var + 1e-5f);
  }
  __syncthreads();
  const int mod = (j0 >= HW) ? 1 : 0;
  const float* g  = mod? ln2g:ln1g;
  const float* bb = mod? ln2b:ln1b;
  const float* exm = ex + ((size_t)mod*B_ + b)*DI;
  for (int it=0; it<48; it++){
    int idx = it*256 + tid;
    int j = idx / DI;
    int d = idx - j*DI;
    float x = v[d][j];
    float o = (x - mu[j])*rs[j]*g[d] + bb[d];
    o *= exm[d];
    yln[((size_t)b*LL + j0 + j)*DI + d] = o;
  }
}

// ---------------- K7: output projection, k-split x2 + atomicAdd ----------------
__global__ __launch_bounds__(128) void k_out(
    const float* __restrict__ yln, const float* __restrict__ Wo, float* __restrict__ out)
{
  __shared__ float lsW[DM*68];
  const int bid  = blockIdx.x;          // 0..511
  const int ks   = bid & 1;             // modality half of the 384-k reduction
  const int rg   = bid >> 1;            // 0..255 row group
  const int row0 = rg * 32;
  const int b    = row0 >> 12;
  const int hw0  = row0 & (HW-1);
  const int tid  = threadIdx.x;
  const int cg = tid & 31, slot = tid >> 5;   // 4 slots
  const int r0 = slot * 8;                    // 8 rows per thread
  float acc[8][3];
  #pragma unroll
  for (int i=0;i<8;i++)
    #pragma unroll
    for (int q=0;q<3;q++) acc[i][q]=0.f;

  const float* xrow = yln + ((size_t)b*LL + (ks ? HW+hw0 : hw0) + r0)*DI;
  for (int c=0;c<3;c++){
    const int colbase = ks*192 + c*64;
    for (int t=tid; t<DM*64; t+=128){
      int dm = t>>6, kkl = t&63;
      lsW[dm*68 + kkl] = Wo[(size_t)dm*384 + colbase + kkl];
    }
    __syncthreads();
    const float* xb = xrow + c*64;
    for (int kk4=0; kk4<16; kk4++){
      float4 xv[8];
      #pragma unroll
      for (int i=0;i<8;i++) xv[i] = *(const float4*)(xb + (size_t)i*DI + kk4*4);
      #pragma unroll
      for (int q=0;q<3;q++){
        const float4 wv = *(const float4*)(&lsW[(cg+32*q)*68 + kk4*4]);
        #pragma unroll
        for (int i=0;i<8;i++){
          acc[i][q] = fmaf(xv[i].x, wv.x, acc[i][q]);
          acc[i][q] = fmaf(xv[i].y, wv.y, acc[i][q]);
          acc[i][q] = fmaf(xv[i].z, wv.z, acc[i][q]);
          acc[i][q] = fmaf(xv[i].w, wv.w, acc[i][q]);
        }
      }
    }
    __syncthreads();
  }
  #pragma unroll
  for (int i=0;i<8;i++){
    float* ob = out + (size_t)(row0 + r0 + i)*DM;
    #pragma unroll
    for (int q=0;q<3;q++) atomicAdd(&ob[cg + 32*q], acc[i][q]);
  }
}

// ---------------- launch ----------------
extern "C" void kernel_launch(void* const* d_in, const int* in_sizes, int n_in,
                              void* d_out, int out_size, void* d_ws, size_t ws_size,
                              hipStream_t stream) {
  const float* x_rgb      = (const float*)d_in[0];
  const float* x_e        = (const float*)d_in[1];
  const float* in_proj_w  = (const float*)d_in[2];
  const float* in_proj_xw = (const float*)d_in[3];
  const float* conv_w     = (const float*)d_in[4];
  const float* conv_b     = (const float*)d_in[5];
  const float* conv_xw    = (const float*)d_in[6];
  const float* conv_xb    = (const float*)d_in[7];
  const float* xpw        = (const float*)d_in[8];
  const float* dtw        = (const float*)d_in[9];
  const float* dtb        = (const float*)d_in[10];
  const float* A_logs     = (const float*)d_in[11];
  const float* Ds         = (const float*)d_in[12];
  const float* ln1_g      = (const float*)d_in[13];
  const float* ln1_b      = (const float*)d_in[14];
  const float* ln2_g      = (const float*)d_in[15];
  const float* ln2_b      = (const float*)d_in[16];
  const float* out_proj_w = (const float*)d_in[17];
  const float* fc1_w1     = (const float*)d_in[18];
  const float* fc1_w2     = (const float*)d_in[19];
  const float* fc2_w1     = (const float*)d_in[20];
  const float* fc2_w2     = (const float*)d_in[21];

  float* ws = (float*)d_ws;
  float* xr_t = ws;                        // 1,572,864
  float* xe_t = ws + 1572864;              // 1,572,864
  float* y0   = ws;                        // 3,145,728 (alias)
  float* seq  = ws + 3145728;              // 3,145,728
  float* yln  = seq;                       // alias
  float* y1   = ws + 6291456;              // 3,145,728
  float* P    = ws + 9437184;              //   458,752
  float* sr   = ws + 9895936;              //       768
  float* ex   = ws + 9896704;              //       768
  float* outp = (float*)d_out;

  k_zero  <<<dim3(3), 256, 0, stream>>>(sr, 768);
  k_inproj<<<dim3(HW/64, B_, 2), 256, 0, stream>>>(x_rgb, x_e, in_proj_w, in_proj_xw, xr_t, xe_t, sr);
  k_conv  <<<dim3(HW/256, DI, B_*2), 256, 0, stream>>>(xr_t, xe_t, conv_w, conv_b, conv_xw, conv_xb, seq);
  k_se    <<<dim3(B_, 2), DI, 0, stream>>>(sr, fc1_w1, fc1_w2, fc2_w1, fc2_w2, ex);
  k_proj  <<<dim3(LL/64, KD, B_), 256, 0, stream>>>(seq, xpw, P);
  k_scan  <<<dim3(B_*KD*DI), 256, 0, stream>>>(seq, P, dtw, dtb, A_logs, Ds, y0, y1);
  k_ln    <<<dim3(LL/64, B_), 256, 0, stream>>>(y0, y1, ln1_g, ln1_b, ln2_g, ln2_b, ex, yln);
  k_zero  <<<dim3((B_*HW*DM + 255)/256), 256, 0, stream>>>(outp, B_*HW*DM);
  k_out   <<<dim3(512), 128, 0, stream>>>(yln, out_proj_w, outp);
}

// Round 13
// 130.031 us; speedup vs baseline: 3.2705x; 1.0665x over previous
//
#include <hip/hip_runtime.h>
#include <math.h>

#define B_  2
#define H_  64
#define W_  64
#define HW  4096
#define DM  96
#define DI  192
#define NS  4
#define RK  6
#define KD  2
#define LL  8192   // 2*HW

__device__ __forceinline__ float sigmoidf_(float x){ return 1.f/(1.f+__expf(-x)); }
__device__ __forceinline__ float4 rev4(float4 v){ return make_float4(v.w,v.z,v.y,v.x); }

// ---------------- K1: input projections -> channel-major [B,DI,HW] + per-block channel sums ----------------
__global__ __launch_bounds__(256) void k_inproj(
    const float* __restrict__ xrgb, const float* __restrict__ xe,
    const float* __restrict__ wr,   const float* __restrict__ we,
    float* __restrict__ xrt, float* __restrict__ xet, float* __restrict__ srp)
{
  __shared__ float lsW[DI*100];
  __shared__ float lsum[DI];
  const int mod = blockIdx.z, b = blockIdx.y;
  const int hw0 = blockIdx.x * 64;
  const float* x  = mod ? xe  : xrgb;
  const float* Wp = mod ? we  : wr;
  float* out      = mod ? xet : xrt;
  const int tid = threadIdx.x;
  for (int t = tid; t < DI*DM; t += 256){
    int di = t / DM, kk = t - di*DM;
    lsW[di*100 + kk] = Wp[t];
  }
  if (tid < DI) lsum[tid] = 0.f;
  const int cg = tid & 31, slot = tid >> 5;   // 8 slots
  const int r0 = slot * 8;
  const float* xb = x + ((size_t)(b*HW) + hw0 + r0)*DM;
  float acc[8][6];
  #pragma unroll
  for (int i=0;i<8;i++)
    #pragma unroll
    for (int q=0;q<6;q++) acc[i][q]=0.f;
  __syncthreads();
  for (int kk4=0; kk4<DM/4; kk4++){
    float4 xv[8];
    #pragma unroll
    for (int i=0;i<8;i++) xv[i] = *(const float4*)(xb + (size_t)i*DM + kk4*4);
    #pragma unroll
    for (int q=0;q<6;q++){
      const float4 wv = *(const float4*)(&lsW[(cg+32*q)*100 + kk4*4]);
      #pragma unroll
      for (int i=0;i<8;i++){
        acc[i][q] = fmaf(xv[i].x, wv.x, acc[i][q]);
        acc[i][q] = fmaf(xv[i].y, wv.y, acc[i][q]);
        acc[i][q] = fmaf(xv[i].z, wv.z, acc[i][q]);
        acc[i][q] = fmaf(xv[i].w, wv.w, acc[i][q]);
      }
    }
  }
  #pragma unroll
  for (int q=0;q<6;q++){
    int di = cg + 32*q;
    float* ob = out + ((size_t)(b*DI + di))*HW + hw0 + r0;
    float ps = 0.f;
    #pragma unroll
    for (int i=0;i<8;i++){ ob[i] = acc[i][q]; ps += acc[i][q]; }
    atomicAdd(&lsum[di], ps);
  }
  __syncthreads();
  if (tid < DI) srp[(((size_t)mod*B_ + b)*64 + blockIdx.x)*DI + tid] = lsum[tid];
}

// ---------------- K2: depthwise 3x3 conv + SiLU -> seq[B,DI,2HW] ----------------
__global__ __launch_bounds__(256) void k_conv(
    const float* __restrict__ xrt, const float* __restrict__ xet,
    const float* __restrict__ cwr, const float* __restrict__ cbr,
    const float* __restrict__ cwe, const float* __restrict__ cbe,
    float* __restrict__ seq)
{
  const int z = blockIdx.z; const int b = z >> 1, mod = z & 1;
  const int d = blockIdx.y;
  const float* in = (mod? xet:xrt) + ((size_t)b*DI + d)*HW;
  const float* wp = (mod? cwe:cwr) + d*9;
  const float  bias = (mod? cbe:cbr)[d];
  const int hw = blockIdx.x*256 + threadIdx.x;
  const int y = hw >> 6, x = hw & 63;
  float w[9];
  #pragma unroll
  for (int i=0;i<9;i++) w[i]=wp[i];
  float acc = bias;
  #pragma unroll
  for (int dy=-1;dy<=1;dy++){
    int yy = y+dy;
    if (yy<0||yy>=H_) continue;
    #pragma unroll
    for (int dx=-1;dx<=1;dx++){
      int xx = x+dx;
      if (xx<0||xx>=W_) continue;
      acc += in[yy*W_+xx]*w[(dy+1)*3 + dx+1];
    }
  }
  float v = acc * sigmoidf_(acc);
  seq[((size_t)b*DI + d)*LL + mod*HW + hw] = v;
}

// ---------------- K4: x_proj -> SoA planes P[bk][14][LL]; also zeros its slice of out ----------------
__global__ __launch_bounds__(256) void k_proj(
    const float* __restrict__ seq, const float* __restrict__ xpw,
    float* __restrict__ P, float* __restrict__ outz)
{
  __shared__ float lw[14*DI];
  __shared__ float part[3][14][66];
  const int b = blockIdx.z, k = blockIdx.y;
  const int j0 = blockIdx.x*64;
  const int tid = threadIdx.x;
  // zero this block's 1536-float slice of out (512 blocks x 1536 = 786432 = B*HW*DM)
  {
    const int bid = (blockIdx.z*KD + blockIdx.y)*gridDim.x + blockIdx.x;
    float* oz = outz + (size_t)bid*1536 + tid;
    #pragma unroll
    for (int q=0;q<6;q++) oz[q*256] = 0.f;
  }
  const int jl = tid & 63, dq = tid >> 6;   // dq: 0..3, 48 channels each
  const int j = j0 + jl;
  for (int t = tid; t < 14*DI; t += 256) lw[t] = xpw[(size_t)k*14*DI + t];
  __syncthreads();
  float acc[14];
  #pragma unroll
  for (int c=0;c<14;c++) acc[c]=0.f;
  const float* sp = seq + (size_t)b*DI*LL + (size_t)(dq*48)*LL + j;
  const float* lwq = lw + dq*48;
  for (int dd=0; dd<48; dd++){
    float s = sp[(size_t)dd*LL];
    #pragma unroll
    for (int cc=0; cc<14; cc++) acc[cc] = fmaf(lwq[cc*DI+dd], s, acc[cc]);
  }
  if (dq){
    #pragma unroll
    for (int cc=0; cc<14; cc++) part[dq-1][cc][jl] = acc[cc];
  }
  __syncthreads();
  if (dq == 0){
    const int bk = b*KD + k;
    float* Pb = P + (size_t)bk*14*LL;
    #pragma unroll
    for (int cc=0; cc<14; cc++){
      float v = acc[cc] + part[0][cc][jl] + part[1][cc][jl] + part[2][cc][jl];
      Pb[(size_t)cc*LL + j] = v;
    }
  }
}

// ---------------- K5: hybrid scan: 4 pos/thread serial + wave shfl-scan, prefetched ----------------
#define GETC(v_, s_) ((s_)==0?(v_).x:((s_)==1?(v_).y:((s_)==2?(v_).z:(v_).w)))
#define NT8 8   // tiles of 1024

template<int KDIR, bool IPOW>
__device__ __forceinline__ void scan_impl(
    const float* __restrict__ sq, const float* __restrict__ Pb,
    const float* A, const float* dwv, float bias, float Dv,
    float* __restrict__ yo, float (*wc)[4][8], int t)
{
  const int lane = t & 63, w = t >> 6;
  float cH[NS] = {0.f,0.f,0.f,0.f};

  int jn = KDIR ? (LL - 4*t - 4) : (4*t);
  float4 pf0 = *(const float4*)(Pb + 0*(size_t)LL + jn);
  float4 pf1 = *(const float4*)(Pb + 1*(size_t)LL + jn);
  float4 pf2 = *(const float4*)(Pb + 2*(size_t)LL + jn);
  float4 pf3 = *(const float4*)(Pb + 3*(size_t)LL + jn);
  float4 pf4 = *(const float4*)(Pb + 4*(size_t)LL + jn);
  float4 pf5 = *(const float4*)(Pb + 5*(size_t)LL + jn);
  float4 pfx = *(const float4*)(sq + jn);

  for (int tt=0; tt<NT8; ++tt){
    const int j0 = jn;
    float4 f0=pf0, f1=pf1, f2=pf2, f3=pf3, f4v=pf4, f5=pf5, fx=pfx;
    float4 b0 = *(const float4*)(Pb + 6*(size_t)LL + j0);
    float4 b1 = *(const float4*)(Pb + 7*(size_t)LL + j0);
    float4 b2 = *(const float4*)(Pb + 8*(size_t)LL + j0);
    float4 b3 = *(const float4*)(Pb + 9*(size_t)LL + j0);
    float4 c0 = *(const float4*)(Pb + 10*(size_t)LL + j0);
    float4 c1 = *(const float4*)(Pb + 11*(size_t)LL + j0);
    float4 c2 = *(const float4*)(Pb + 12*(size_t)LL + j0);
    float4 c3 = *(const float4*)(Pb + 13*(size_t)LL + j0);

    if (tt+1 < NT8){
      jn = KDIR ? (LL - 1024*(tt+1) - 4*t - 4) : (1024*(tt+1) + 4*t);
      pf0 = *(const float4*)(Pb + 0*(size_t)LL + jn);
      pf1 = *(const float4*)(Pb + 1*(size_t)LL + jn);
      pf2 = *(const float4*)(Pb + 2*(size_t)LL + jn);
      pf3 = *(const float4*)(Pb + 3*(size_t)LL + jn);
      pf4 = *(const float4*)(Pb + 4*(size_t)LL + jn);
      pf5 = *(const float4*)(Pb + 5*(size_t)LL + jn);
      pfx = *(const float4*)(sq + jn);
    }

    if (KDIR){
      f0=rev4(f0); f1=rev4(f1); f2=rev4(f2); f3=rev4(f3); f4v=rev4(f4v); f5=rev4(f5);
      fx=rev4(fx);
      b0=rev4(b0); b1=rev4(b1); b2=rev4(b2); b3=rev4(b3);
      c0=rev4(c0); c1=rev4(c1); c2=rev4(c2); c3=rev4(c3);
    }

    float del[4], du[4], aP0[4], aP1[4], aP2[4], aP3[4];
    #pragma unroll
    for (int i=0;i<4;i++){
      float acc = bias;
      acc = fmaf(dwv[0],GETC(f0,i),acc); acc = fmaf(dwv[1],GETC(f1,i),acc);
      acc = fmaf(dwv[2],GETC(f2,i),acc); acc = fmaf(dwv[3],GETC(f3,i),acc);
      acc = fmaf(dwv[4],GETC(f4v,i),acc); acc = fmaf(dwv[5],GETC(f5,i),acc);
      if (IPOW){
        float ex_ = __expf(acc);
        del[i] = (acc > 20.f) ? acc : __logf(1.f + ex_);
        float a0 = 1.f/(1.f + ex_);        // exp(-softplus(acc)) exactly
        float a1 = a0*a0;
        aP0[i]=a0; aP1[i]=a1; aP2[i]=a1*a0; aP3[i]=a1*a1;
      } else {
        float dl = (acc > 20.f) ? acc : __logf(1.f + __expf(acc));
        del[i] = dl;
        aP0[i]=__expf(dl*A[0]); aP1[i]=__expf(dl*A[1]);
        aP2[i]=__expf(dl*A[2]); aP3[i]=__expf(dl*A[3]);
      }
      du[i]  = del[i]*GETC(fx,i);
    }

    float lA[NS][4], lH[NS][4];
    #pragma unroll
    for (int n=0;n<NS;n++){
      float rA=1.f, rH=0.f;
      #pragma unroll
      for (int i=0;i<4;i++){
        float Bi = GETC((n==0?b0:n==1?b1:n==2?b2:b3), i);
        float ai = (n==0? aP0[i] : n==1? aP1[i] : n==2? aP2[i] : aP3[i]);
        rH = fmaf(ai, rH, du[i]*Bi);
        rA *= ai;
        lA[n][i]=rA; lH[n][i]=rH;
      }
    }

    float sA[NS], sH[NS];
    #pragma unroll
    for (int n=0;n<NS;n++){ sA[n]=lA[n][3]; sH[n]=lH[n][3]; }
    #pragma unroll
    for (int s=1; s<64; s<<=1){
      float pa[NS], ph[NS];
      #pragma unroll
      for (int n=0;n<NS;n++){ pa[n]=__shfl_up(sA[n],(unsigned)s,64); ph[n]=__shfl_up(sH[n],(unsigned)s,64); }
      if (lane >= s){
        #pragma unroll
        for (int n=0;n<NS;n++){ sH[n]=fmaf(sA[n],ph[n],sH[n]); sA[n]*=pa[n]; }
      }
    }
    float eA[NS], eH[NS];
    #pragma unroll
    for (int n=0;n<NS;n++){
      float xa = __shfl_up(sA[n],1u,64), xh = __shfl_up(sH[n],1u,64);
      eA[n] = lane ? xa : 1.f;
      eH[n] = lane ? xh : 0.f;
    }

    const int buf = tt & 1;
    if (lane == 63){
      #pragma unroll
      for (int n=0;n<NS;n++){ wc[buf][w][n]=sA[n]; wc[buf][w][4+n]=sH[n]; }
    }
    __syncthreads();

    float WA[NS]={1.f,1.f,1.f,1.f}, WH[NS]={0.f,0.f,0.f,0.f};
    float TA[NS]={1.f,1.f,1.f,1.f}, TH[NS]={0.f,0.f,0.f,0.f};
    #pragma unroll
    for (int ww=0; ww<4; ww++){
      #pragma unroll
      for (int n=0;n<NS;n++){
        float qa = wc[buf][ww][n], qh = wc[buf][ww][4+n];
        if (ww < w){ WH[n]=fmaf(qa,WH[n],qh); WA[n]*=qa; }
        TH[n]=fmaf(qa,TH[n],qh); TA[n]*=qa;
      }
    }

    float PH[NS];
    #pragma unroll
    for (int n=0;n<NS;n++){
      float GH = fmaf(WA[n], cH[n], WH[n]);
      PH[n] = fmaf(eA[n], GH, eH[n]);
    }

    float yv[4];
    #pragma unroll
    for (int i=0;i<4;i++){
      float y = Dv*GETC(fx,i);
      #pragma unroll
      for (int n=0;n<NS;n++){
        float h = fmaf(lA[n][i], PH[n], lH[n][i]);
        float Ci = GETC((n==0?c0:n==1?c1:n==2?c2:c3), i);
        y = fmaf(Ci, h, y);
      }
      yv[i] = y;
    }
    float4 o = make_float4(yv[0],yv[1],yv[2],yv[3]);
    if (KDIR) o = rev4(o);
    *(float4*)(yo + j0) = o;

    #pragma unroll
    for (int n=0;n<NS;n++) cH[n] = fmaf(TA[n], cH[n], TH[n]);
  }
}

__global__ __launch_bounds__(256, 3) void k_scan(
    const float* __restrict__ seq,  const float* __restrict__ P,
    const float* __restrict__ dtw,  const float* __restrict__ dtb,
    const float* __restrict__ Alogs,const float* __restrict__ Dsp,
    float* __restrict__ y0, float* __restrict__ y1)
{
  const int gid = blockIdx.x;
  const int d = gid % DI;
  const int k = (gid / DI) % KD;
  const int b = gid / (DI*KD);
  const int t = threadIdx.x;
  const int kd = k*DI + d;
  float A[NS];
  #pragma unroll
  for (int n=0;n<NS;n++) A[n] = -__expf(Alogs[kd*NS+n]);
  float dwv[RK];
  #pragma unroll
  for (int r=0;r<RK;r++) dwv[r] = dtw[kd*RK+r];
  const float bias = dtb[kd];
  const float Dv   = Dsp[kd];
  const float* sq = seq + ((size_t)b*DI + d)*LL;
  const int bk = b*KD + k;
  const float* Pb = P + (size_t)bk*14*LL;
  float* yo = (k ? y1 : y0) + ((size_t)b*DI + d)*LL;

  __shared__ float wc[2][4][8];

  const float tol = 1e-5f;
  const bool ipow = (fabsf(A[0]+1.f)<tol) && (fabsf(A[1]+2.f)<4.f*tol)
                 && (fabsf(A[2]+3.f)<tol*8.f) && (fabsf(A[3]+4.f)<tol*8.f);

  if (ipow){
    if (k == 0) scan_impl<0,true>(sq, Pb, A, dwv, bias, Dv, yo, wc, t);
    else        scan_impl<1,true>(sq, Pb, A, dwv, bias, Dv, yo, wc, t);
  } else {
    if (k == 0) scan_impl<0,false>(sq, Pb, A, dwv, bias, Dv, yo, wc, t);
    else        scan_impl<1,false>(sq, Pb, A, dwv, bias, Dv, yo, wc, t);
  }
}

// ---------------- K6: merge + LayerNorm + inline SE -> yln[B,L,DI] ----------------
__global__ __launch_bounds__(256) void k_ln(
    const float* __restrict__ y0, const float* __restrict__ y1,
    const float* __restrict__ ln1g, const float* __restrict__ ln1b,
    const float* __restrict__ ln2g, const float* __restrict__ ln2b,
    const float* __restrict__ f11, const float* __restrict__ f12,
    const float* __restrict__ f21, const float* __restrict__ f22,
    const float* __restrict__ srp, float* __restrict__ yln)
{
  const int b  = blockIdx.y;
  const int j0 = blockIdx.x*64;
  const int mod = (j0 >= HW) ? 1 : 0;
  __shared__ float v[DI][65];
  __shared__ float ps1[4][64], ps2[4][64];
  __shared__ float mu[64], rs[64];
  __shared__ float sm[DI];
  __shared__ float hid[12];
  __shared__ float exs[DI];
  const int tid = threadIdx.x;
  const int jl = tid & 63, ds = tid >> 6;

  // phase 1: channel means from partial sums + stage v
  if (tid < DI){
    const float* pp = srp + ((size_t)(mod*B_ + b)*64)*DI + tid;
    float s = 0.f;
    for (int q=0;q<64;q++) s += pp[(size_t)q*DI];
    sm[tid] = s * (1.f/HW);
  }
  const float* p0 = y0 + (size_t)b*DI*LL + j0;
  const float* p1 = y1 + (size_t)b*DI*LL + j0;
  for (int it=0; it<48; it++){
    int d = ds*48 + it;
    v[d][jl] = p0[(size_t)d*LL + jl] + p1[(size_t)d*LL + jl];
  }
  __syncthreads();

  // phase 2: SE hidden layer + LN stats
  const float* f1 = mod? f21:f11;
  const float* f2 = mod? f22:f12;
  if (tid < 12){
    float a=0.f;
    for (int dd=0; dd<DI; dd++) a += f1[tid*DI+dd]*sm[dd];
    hid[tid] = a * sigmoidf_(a);
  }
  float s1=0.f, s2=0.f;
  for (int it=0; it<48; it++){
    float x = v[ds*48+it][jl];
    s1 += x; s2 += x*x;
  }
  ps1[ds][jl]=s1; ps2[ds][jl]=s2;
  __syncthreads();

  // phase 3: SE output + mu/rs
  if (tid < DI){
    float a=0.f;
    #pragma unroll
    for (int h=0; h<12; h++) a += f2[tid*12+h]*hid[h];
    exs[tid] = sigmoidf_(a);
  }
  if (tid < 64){
    float t1 = ps1[0][tid]+ps1[1][tid]+ps1[2][tid]+ps1[3][tid];
    float t2 = ps2[0][tid]+ps2[1][tid]+ps2[2][tid]+ps2[3][tid];
    float m  = t1*(1.f/DI);
    float var= t2*(1.f/DI) - m*m;
    mu[tid]=m; rs[tid]=rsqrtf(var + 1e-5f);
  }
  __syncthreads();

  const float* g  = mod? ln2g:ln1g;
  const float* bb = mod? ln2b:ln1b;
  for (int it=0; it<48; it++){
    int idx = it*256 + tid;
    int j = idx / DI;
    int d = idx - j*DI;
    float x = v[d][j];
    float o = (x - mu[j])*rs[j]*g[d] + bb[d];
    o *= exs[d];
    yln[((size_t)b*LL + j0 + j)*DI + d] = o;
  }
}

// ---------------- K7: output projection, k-split x2 + atomicAdd ----------------
__global__ __launch_bounds__(128) void k_out(
    const float* __restrict__ yln, const float* __restrict__ Wo, float* __restrict__ out)
{
  __shared__ float lsW[DM*68];
  const int bid  = blockIdx.x;          // 0..511
  const int ks   = bid & 1;             // modality half of the 384-k reduction
  const int rg   = bid >> 1;            // 0..255 row group
  const int row0 = rg * 32;
  const int b    = row0 >> 12;
  const int hw0  = row0 & (HW-1);
  const int tid  = threadIdx.x;
  const int cg = tid & 31, slot = tid >> 5;   // 4 slots
  const int r0 = slot * 8;                    // 8 rows per thread
  float acc[8][3];
  #pragma unroll
  for (int i=0;i<8;i++)
    #pragma unroll
    for (int q=0;q<3;q++) acc[i][q]=0.f;

  const float* xrow = yln + ((size_t)b*LL + (ks ? HW+hw0 : hw0) + r0)*DI;
  for (int c=0;c<3;c++){
    const int colbase = ks*192 + c*64;
    for (int t=tid; t<DM*64; t+=128){
      int dm = t>>6, kkl = t&63;
      lsW[dm*68 + kkl] = Wo[(size_t)dm*384 + colbase + kkl];
    }
    __syncthreads();
    const float* xb = xrow + c*64;
    for (int kk4=0; kk4<16; kk4++){
      float4 xv[8];
      #pragma unroll
      for (int i=0;i<8;i++) xv[i] = *(const float4*)(xb + (size_t)i*DI + kk4*4);
      #pragma unroll
      for (int q=0;q<3;q++){
        const float4 wv = *(const float4*)(&lsW[(cg+32*q)*68 + kk4*4]);
        #pragma unroll
        for (int i=0;i<8;i++){
          acc[i][q] = fmaf(xv[i].x, wv.x, acc[i][q]);
          acc[i][q] = fmaf(xv[i].y, wv.y, acc[i][q]);
          acc[i][q] = fmaf(xv[i].z, wv.z, acc[i][q]);
          acc[i][q] = fmaf(xv[i].w, wv.w, acc[i][q]);
        }
      }
    }
    __syncthreads();
  }
  #pragma unroll
  for (int i=0;i<8;i++){
    float* ob = out + (size_t)(row0 + r0 + i)*DM;
    #pragma unroll
    for (int q=0;q<3;q++) atomicAdd(&ob[cg + 32*q], acc[i][q]);
  }
}

// ---------------- launch ----------------
extern "C" void kernel_launch(void* const* d_in, const int* in_sizes, int n_in,
                              void* d_out, int out_size, void* d_ws, size_t ws_size,
                              hipStream_t stream) {
  const float* x_rgb      = (const float*)d_in[0];
  const float* x_e        = (const float*)d_in[1];
  const float* in_proj_w  = (const float*)d_in[2];
  const float* in_proj_xw = (const float*)d_in[3];
  const float* conv_w     = (const float*)d_in[4];
  const float* conv_b     = (const float*)d_in[5];
  const float* conv_xw    = (const float*)d_in[6];
  const float* conv_xb    = (const float*)d_in[7];
  const float* xpw        = (const float*)d_in[8];
  const float* dtw        = (const float*)d_in[9];
  const float* dtb        = (const float*)d_in[10];
  const float* A_logs     = (const float*)d_in[11];
  const float* Ds         = (const float*)d_in[12];
  const float* ln1_g      = (const float*)d_in[13];
  const float* ln1_b      = (const float*)d_in[14];
  const float* ln2_g      = (const float*)d_in[15];
  const float* ln2_b      = (const float*)d_in[16];
  const float* out_proj_w = (const float*)d_in[17];
  const float* fc1_w1     = (const float*)d_in[18];
  const float* fc1_w2     = (const float*)d_in[19];
  const float* fc2_w1     = (const float*)d_in[20];
  const float* fc2_w2     = (const float*)d_in[21];

  float* ws = (float*)d_ws;
  float* xr_t = ws;                        // 1,572,864
  float* xe_t = ws + 1572864;              // 1,572,864
  float* y0   = ws;                        // 3,145,728 (alias)
  float* seq  = ws + 3145728;              // 3,145,728
  float* yln  = seq;                       // alias
  float* y1   = ws + 6291456;              // 3,145,728
  float* P    = ws + 9437184;              //   458,752
  float* srp  = ws + 9895936;              //    49,152 (4 x 64 x 192 partial sums)
  float* outp = (float*)d_out;

  k_inproj<<<dim3(HW/64, B_, 2), 256, 0, stream>>>(x_rgb, x_e, in_proj_w, in_proj_xw, xr_t, xe_t, srp);
  k_conv  <<<dim3(HW/256, DI, B_*2), 256, 0, stream>>>(xr_t, xe_t, conv_w, conv_b, conv_xw, conv_xb, seq);
  k_proj  <<<dim3(LL/64, KD, B_), 256, 0, stream>>>(seq, xpw, P, outp);
  k_scan  <<<dim3(B_*KD*DI), 256, 0, stream>>>(seq, P, dtw, dtb, A_logs, Ds, y0, y1);
  k_ln    <<<dim3(LL/64, B_), 256, 0, stream>>>(y0, y1, ln1_g, ln1_b, ln2_g, ln2_b,
                                                fc1_w1, fc1_w2, fc2_w1, fc2_w2, srp, yln);
  k_out   <<<dim3(512), 128, 0, stream>>>(yln, out_proj_w, outp);
}